// Round 9
// baseline (733.359 us; speedup 1.0000x reference)
//
#include <hip/hip_runtime.h>
#include <cstdint>
#include <cstddef>

#define B_    4096
#define LAT   64
#define FRAME 512
#define HID   1024
#define NE    8
#define GH    128
#define IN1   576   // LAT + FRAME
#define IN2   1088  // LAT + HID

typedef _Float16 half8 __attribute__((ext_vector_type(8)));
typedef _Float16 half4 __attribute__((ext_vector_type(4)));
typedef float  f32x4  __attribute__((ext_vector_type(4)));

// async global->LDS, 16B per lane; LDS dest = wave-uniform base + lane*16
__device__ inline void async16(const void* g, void* l) {
  __builtin_amdgcn_global_load_lds(
      (__attribute__((address_space(1))) void*)(void*)g,
      (__attribute__((address_space(3))) void*)l, 16, 0, 0);
}

__device__ inline float elu(float v) { return v > 0.f ? v : expm1f(v); }

// ---- unified weight prep: all 5 transpose+casts (fp32 [K][N] -> f16 [N][K]) ----
__global__ __launch_bounds__(256) void prep_weights(
    const float* __restrict__ w0, const float* __restrict__ w1,
    const float* __restrict__ w2, const float* __restrict__ gw1,
    const float* __restrict__ gw2,
    _Float16* __restrict__ Wt0, _Float16* __restrict__ Wt1,
    _Float16* __restrict__ Wt2, _Float16* __restrict__ gw1T,
    _Float16* __restrict__ gw2T)
{
  __shared__ float t[64][65];
  int bid = blockIdx.x;
  const float* in; _Float16* out; int K, N, kt, nt;
  if (bid < 1152) {
    const int e = bid / 144, rem = bid % 144;
    K = IN1; N = HID; kt = rem / 16; nt = rem % 16;
    in = w0 + (size_t)e * K * N; out = Wt0 + (size_t)e * N * K;
  } else if (bid < 3328) {
    const int i = bid - 1152, e = i / 272, rem = i % 272;
    K = IN2; N = HID; kt = rem / 16; nt = rem % 16;
    in = w1 + (size_t)e * K * N; out = Wt1 + (size_t)e * N * K;
  } else if (bid < 4416) {
    const int i = bid - 3328, e = i / 136, rem = i % 136;
    K = IN2; N = FRAME; kt = rem / 8; nt = rem % 8;
    in = w2 + (size_t)e * K * N; out = Wt2 + (size_t)e * N * K;
  } else if (bid < 4434) {
    const int i = bid - 4416;
    K = IN1; N = GH; kt = i / 2; nt = i % 2;
    in = gw1; out = gw1T;
  } else {
    const int i = bid - 4434;
    K = GH; N = GH; kt = i / 2; nt = i % 2;
    in = gw2; out = gw2T;
  }
  const int k0 = kt * 64, n0 = nt * 64;
  const int lr = threadIdx.x >> 4;          // 0..15
  const int lc = (threadIdx.x & 15) * 4;    // 0..60
  #pragma unroll
  for (int rr = 0; rr < 4; ++rr) {
    const int k = rr * 16 + lr;
    f32x4 v = *(const f32x4*)(in + (size_t)(k0 + k) * N + n0 + lc);
    t[k][lc] = v[0]; t[k][lc + 1] = v[1]; t[k][lc + 2] = v[2]; t[k][lc + 3] = v[3];
  }
  __syncthreads();
  #pragma unroll
  for (int rr = 0; rr < 4; ++rr) {
    const int n = rr * 16 + lr;
    half4 o;
    #pragma unroll
    for (int q = 0; q < 4; ++q) o[q] = (_Float16)t[lc + q][n];
    *(half4*)(out + (size_t)(n0 + n) * K + k0 + lc) = o;
  }
}

// ---------------- gate MLP via f16 MFMA -> coef [B, 8] fp32 ----------------
__global__ __launch_bounds__(256) void gate_mfma(
    const float* __restrict__ z, const float* __restrict__ c,
    const _Float16* __restrict__ gw1T,   // [128][576]
    const _Float16* __restrict__ gw2T,   // [128][128]
    const float* __restrict__ gb1, const float* __restrict__ gb2,
    const float* __restrict__ gw3, const float* __restrict__ gb3,
    float* __restrict__ coef)
{
  __shared__ _Float16 h_lds[64][136];
  __shared__ float    h2_lds[64][129];
  __shared__ float    gw3s[128 * 8];
  const int tid = threadIdx.x;
  const int wave = tid >> 6, lane = tid & 63;
  const int quad = lane >> 4, l16 = lane & 15;
  const int r0 = blockIdx.x * 64;

  for (int i = tid; i < 128 * 8; i += 256) gw3s[i] = gw3[i];

  f32x4 acc[8];
  #pragma unroll
  for (int nt = 0; nt < 8; ++nt)
    #pragma unroll
    for (int r = 0; r < 4; ++r) acc[nt][r] = 0.f;

  #pragma unroll 2
  for (int s = 0; s < 18; ++s) {
    const int k0 = s * 32;
    half8 af;
    {
      const size_t row = r0 + wave * 16 + l16;
      const float* src = (k0 < LAT) ? z + row * LAT + k0 + quad * 8
                                    : c + row * FRAME + (k0 - LAT) + quad * 8;
      f32x4 lo = *(const f32x4*)src, hi = *(const f32x4*)(src + 4);
      #pragma unroll
      for (int j = 0; j < 4; ++j) { af[j] = (_Float16)lo[j]; af[j + 4] = (_Float16)hi[j]; }
    }
    half8 bfr[8];
    #pragma unroll
    for (int nt = 0; nt < 8; ++nt)
      bfr[nt] = *(const half8*)(gw1T + (size_t)(nt * 16 + l16) * 576 + k0 + quad * 8);
    #pragma unroll
    for (int nt = 0; nt < 8; ++nt)
      acc[nt] = __builtin_amdgcn_mfma_f32_16x16x32_f16(af, bfr[nt], acc[nt], 0, 0, 0);
  }
  #pragma unroll
  for (int nt = 0; nt < 8; ++nt)
    #pragma unroll
    for (int r = 0; r < 4; ++r) {
      const int rowl = wave * 16 + quad * 4 + r;
      const int col = nt * 16 + l16;
      h_lds[rowl][col] = (_Float16)elu(acc[nt][r] + gb1[col]);
    }
  __syncthreads();

  f32x4 acc2[8];
  #pragma unroll
  for (int nt = 0; nt < 8; ++nt)
    #pragma unroll
    for (int r = 0; r < 4; ++r) acc2[nt][r] = 0.f;
  #pragma unroll
  for (int s = 0; s < 4; ++s) {
    const int k0 = s * 32;
    half8 af = *(const half8*)&h_lds[wave * 16 + l16][k0 + quad * 8];
    half8 bfr[8];
    #pragma unroll
    for (int nt = 0; nt < 8; ++nt)
      bfr[nt] = *(const half8*)(gw2T + (size_t)(nt * 16 + l16) * 128 + k0 + quad * 8);
    #pragma unroll
    for (int nt = 0; nt < 8; ++nt)
      acc2[nt] = __builtin_amdgcn_mfma_f32_16x16x32_f16(af, bfr[nt], acc2[nt], 0, 0, 0);
  }
  #pragma unroll
  for (int nt = 0; nt < 8; ++nt)
    #pragma unroll
    for (int r = 0; r < 4; ++r) {
      const int rowl = wave * 16 + quad * 4 + r;
      const int col = nt * 16 + l16;
      h2_lds[rowl][col] = elu(acc2[nt][r] + gb2[col]);
    }
  __syncthreads();

  {
    const int row = tid >> 2, q = tid & 3;
    float l2v[2] = { gb3[2 * q], gb3[2 * q + 1] };
    for (int k = 0; k < 128; ++k) {
      const float hv = h2_lds[row][k];
      l2v[0] += hv * gw3s[k * 8 + 2 * q];
      l2v[1] += hv * gw3s[k * 8 + 2 * q + 1];
    }
    float m = fmaxf(l2v[0], l2v[1]);
    m = fmaxf(m, __shfl_xor(m, 1));
    m = fmaxf(m, __shfl_xor(m, 2));
    float e0 = expf(l2v[0] - m), e1 = expf(l2v[1] - m);
    float s = e0 + e1;
    s += __shfl_xor(s, 1);
    s += __shfl_xor(s, 2);
    const float inv = 1.f / s;
    float2 o = { e0 * inv, e1 * inv };
    *(float2*)&coef[(size_t)(r0 + row) * NE + 2 * q] = o;
  }
}

// ---- x1 f16 = [z | c], vectorized x4 ----
__global__ __launch_bounds__(256) void build_x1(
    const float* __restrict__ z, const float* __restrict__ c,
    _Float16* __restrict__ x1)
{
  const int idx4 = blockIdx.x * 256 + threadIdx.x;   // B_*IN1/4 exact
  const int b = idx4 / (IN1 / 4), j = (idx4 - b * (IN1 / 4)) * 4;
  f32x4 v = (j < LAT) ? *(const f32x4*)(z + (size_t)b * LAT + j)
                      : *(const f32x4*)(c + (size_t)b * FRAME + (j - LAT));
  half4 o;
  #pragma unroll
  for (int q = 0; q < 4; ++q) o[q] = (_Float16)v[q];
  *(half4*)(x1 + (size_t)b * IN1 + j) = o;
}

// -------- TALL MoE GEMM: 256x128 tile, wave = 128x64 (mi=8, ni=4) --------
// Same r6-verified 16x16x32 read pattern/swizzle; A staged once per k0,
// B double-buffered across the EG-expert loop. part[z] for expert-group z.
template<int KDIM, int NOUT, int EG>
__global__ __launch_bounds__(256, 2) void gemm_tall(
    const _Float16* __restrict__ X,     // [B][KDIM]
    const _Float16* __restrict__ Wt,    // [NE][NOUT][KDIM]
    const float* __restrict__ coef,     // [B][8]
    const float* __restrict__ bias,     // [8][NOUT]
    float* __restrict__ part)           // [NE/EG][B][NOUT]
{
  __shared__ __align__(16) _Float16 As[256 * 64];
  __shared__ __align__(16) _Float16 Bs[2][128 * 64];
  __shared__ float coefS[256 * EG];
  __shared__ float biasS[EG * 128];

  const int tid = threadIdx.x;
  const int wave = tid >> 6, lane = tid & 63;
  const int wm = wave & 1, wn = wave >> 1;
  const int quad = lane >> 4, l16 = lane & 15;
  const int bm0 = blockIdx.x * 256, bn0 = blockIdx.y * 128;
  const int ebase = blockIdx.z * EG;

  for (int i = tid; i < 256 * EG; i += 256)
    coefS[i] = coef[(size_t)(bm0 + i / EG) * NE + ebase + (i % EG)];
  for (int i = tid; i < EG * 128; i += 256)
    biasS[i] = bias[(size_t)(ebase + (i >> 7)) * NOUT + bn0 + (i & 127)];
  __syncthreads();

  // per-lane coef: A-fragment row = wm*128 + mi*16 + l16
  _Float16 ch[8][EG];
  #pragma unroll
  for (int mi = 0; mi < 8; ++mi)
    #pragma unroll
    for (int e = 0; e < EG; ++e)
      ch[mi][e] = (_Float16)coefS[(wm * 128 + mi * 16 + l16) * EG + e];

  f32x4 acc[8][4];
  #pragma unroll
  for (int mi = 0; mi < 8; ++mi)
    #pragma unroll
    for (int ni = 0; ni < 4; ++ni)
      #pragma unroll
      for (int r = 0; r < 4; ++r) acc[mi][ni][r] = 0.f;

  const int srow  = wave * 8 + (lane >> 3);                  // + it*32
  const int skoff = (((lane & 7) ^ ((lane >> 3) & 7)) * 8);  // swizzled src granule

  constexpr int K0S = KDIM / 64;
  for (int k0i = 0; k0i < K0S; ++k0i) {
    const int k0 = k0i * 64;
    // stage A (256 rows, once per k0) and first expert's B
    #pragma unroll
    for (int it = 0; it < 8; ++it)
      async16(X + (size_t)(bm0 + it * 32 + srow) * KDIM + k0 + skoff,
              &As[it * 2048 + wave * 512]);
    {
      const size_t eoff = (size_t)ebase * NOUT * KDIM;
      #pragma unroll
      for (int it = 0; it < 4; ++it)
        async16(Wt + eoff + (size_t)(bn0 + it * 32 + srow) * KDIM + k0 + skoff,
                &Bs[0][it * 2048 + wave * 512]);
    }
    __syncthreads();

    // A fragments for this k0, reused across the expert group
    half8 af[2][8];
    #pragma unroll
    for (int ks = 0; ks < 2; ++ks)
      #pragma unroll
      for (int mi = 0; mi < 8; ++mi) {
        const int r = wm * 128 + mi * 16 + l16;
        const int g = (ks * 4 + quad) ^ (r & 7);
        af[ks][mi] = *(const half8*)&As[r * 64 + g * 8];
      }

    #pragma unroll
    for (int eo = 0; eo < EG; ++eo) {
      if (eo + 1 < EG) {   // prefetch next expert's B into other buffer
        const size_t eoff = (size_t)(ebase + eo + 1) * NOUT * KDIM;
        #pragma unroll
        for (int it = 0; it < 4; ++it)
          async16(Wt + eoff + (size_t)(bn0 + it * 32 + srow) * KDIM + k0 + skoff,
                  &Bs[(eo + 1) & 1][it * 2048 + wave * 512]);
      }
      const _Float16* bsrc = Bs[eo & 1];
      #pragma unroll
      for (int ks = 0; ks < 2; ++ks) {
        half8 bv[4];
        #pragma unroll
        for (int ni = 0; ni < 4; ++ni) {
          const int r = wn * 64 + ni * 16 + l16;
          const int g = (ks * 4 + quad) ^ (r & 7);
          bv[ni] = *(const half8*)&bsrc[r * 64 + g * 8];
        }
        #pragma unroll
        for (int mi = 0; mi < 8; ++mi) {
          const half8 afs = af[ks][mi] * ch[mi][eo];
          #pragma unroll
          for (int ni = 0; ni < 4; ++ni)
            acc[mi][ni] = __builtin_amdgcn_mfma_f32_16x16x32_f16(
                afs, bv[ni], acc[mi][ni], 0, 0, 0);
        }
      }
      __syncthreads();   // protects Bs reuse and As for next k0's staging
    }
  }

  // epilogue: + group's coef@bias; write partial (deterministic)
  float* po = part + (size_t)blockIdx.z * B_ * NOUT;
  #pragma unroll
  for (int mi = 0; mi < 8; ++mi)
    #pragma unroll
    for (int r = 0; r < 4; ++r) {
      const int m_loc = wm * 128 + mi * 16 + quad * 4 + r;
      #pragma unroll
      for (int ni = 0; ni < 4; ++ni) {
        const int n_loc = wn * 64 + ni * 16 + l16;
        float v = acc[mi][ni][r];
        #pragma unroll
        for (int e = 0; e < EG; ++e)
          v += coefS[m_loc * EG + e] * biasS[e * 128 + n_loc];
        po[(size_t)(bm0 + m_loc) * NOUT + bn0 + n_loc] = v;
      }
    }
}

// -------- 128x128 MoE GEMM (r6-verified config), used for layer 3 --------
template<int KDIM, int NOUT, int EG>
__global__ __launch_bounds__(256, 2) void gemm_moe(
    const _Float16* __restrict__ X,
    const _Float16* __restrict__ Wt,
    const float* __restrict__ coef,
    const float* __restrict__ bias,
    float* __restrict__ part)
{
  __shared__ __align__(16) _Float16 As[128 * 64];
  __shared__ __align__(16) _Float16 Bs[2][128 * 64];
  __shared__ float coefS[128 * EG];
  __shared__ float biasS[EG * 128];

  const int tid = threadIdx.x;
  const int wave = tid >> 6, lane = tid & 63;
  const int wm = wave & 1, wn = wave >> 1;
  const int quad = lane >> 4, l16 = lane & 15;
  const int bm0 = blockIdx.x * 128, bn0 = blockIdx.y * 128;
  const int ebase = blockIdx.z * EG;

  for (int i = tid; i < 128 * EG; i += 256)
    coefS[i] = coef[(size_t)(bm0 + i / EG) * NE + ebase + (i % EG)];
  for (int i = tid; i < EG * 128; i += 256)
    biasS[i] = bias[(size_t)(ebase + (i >> 7)) * NOUT + bn0 + (i & 127)];
  __syncthreads();

  _Float16 ch[4][EG];
  #pragma unroll
  for (int mi = 0; mi < 4; ++mi)
    #pragma unroll
    for (int e = 0; e < EG; ++e)
      ch[mi][e] = (_Float16)coefS[(wm * 64 + mi * 16 + l16) * EG + e];

  f32x4 acc[4][4];
  #pragma unroll
  for (int mi = 0; mi < 4; ++mi)
    #pragma unroll
    for (int ni = 0; ni < 4; ++ni)
      #pragma unroll
      for (int r = 0; r < 4; ++r) acc[mi][ni][r] = 0.f;

  const int srow  = wave * 8 + (lane >> 3);
  const int skoff = (((lane & 7) ^ ((lane >> 3) & 7)) * 8);

  constexpr int K0S = KDIM / 64;
  for (int k0i = 0; k0i < K0S; ++k0i) {
    const int k0 = k0i * 64;
    #pragma unroll
    for (int it = 0; it < 4; ++it)
      async16(X + (size_t)(bm0 + it * 32 + srow) * KDIM + k0 + skoff,
              &As[it * 2048 + wave * 512]);
    {
      const size_t eoff = (size_t)ebase * NOUT * KDIM;
      #pragma unroll
      for (int it = 0; it < 4; ++it)
        async16(Wt + eoff + (size_t)(bn0 + it * 32 + srow) * KDIM + k0 + skoff,
                &Bs[0][it * 2048 + wave * 512]);
    }
    __syncthreads();

    half8 af[2][4];
    #pragma unroll
    for (int ks = 0; ks < 2; ++ks)
      #pragma unroll
      for (int mi = 0; mi < 4; ++mi) {
        const int r = wm * 64 + mi * 16 + l16;
        const int g = (ks * 4 + quad) ^ (r & 7);
        af[ks][mi] = *(const half8*)&As[r * 64 + g * 8];
      }

    #pragma unroll
    for (int eo = 0; eo < EG; ++eo) {
      if (eo + 1 < EG) {
        const size_t eoff = (size_t)(ebase + eo + 1) * NOUT * KDIM;
        #pragma unroll
        for (int it = 0; it < 4; ++it)
          async16(Wt + eoff + (size_t)(bn0 + it * 32 + srow) * KDIM + k0 + skoff,
                  &Bs[(eo + 1) & 1][it * 2048 + wave * 512]);
      }
      const _Float16* bsrc = Bs[eo & 1];
      #pragma unroll
      for (int ks = 0; ks < 2; ++ks) {
        half8 bv[4];
        #pragma unroll
        for (int ni = 0; ni < 4; ++ni) {
          const int r = wn * 64 + ni * 16 + l16;
          const int g = (ks * 4 + quad) ^ (r & 7);
          bv[ni] = *(const half8*)&bsrc[r * 64 + g * 8];
        }
        #pragma unroll
        for (int mi = 0; mi < 4; ++mi) {
          const half8 afs = af[ks][mi] * ch[mi][eo];
          #pragma unroll
          for (int ni = 0; ni < 4; ++ni)
            acc[mi][ni] = __builtin_amdgcn_mfma_f32_16x16x32_f16(
                afs, bv[ni], acc[mi][ni], 0, 0, 0);
        }
      }
      __syncthreads();
    }
  }

  float* po = part + (size_t)blockIdx.z * B_ * NOUT;
  #pragma unroll
  for (int mi = 0; mi < 4; ++mi)
    #pragma unroll
    for (int r = 0; r < 4; ++r) {
      const int m_loc = wm * 64 + mi * 16 + quad * 4 + r;
      #pragma unroll
      for (int ni = 0; ni < 4; ++ni) {
        const int n_loc = wn * 64 + ni * 16 + l16;
        float v = acc[mi][ni][r];
        #pragma unroll
        for (int e = 0; e < EG; ++e)
          v += coefS[m_loc * EG + e] * biasS[e * 128 + n_loc];
        po[(size_t)(bm0 + m_loc) * NOUT + bn0 + n_loc] = v;
      }
    }
}

// ---- expand: x_next = f16( j<64 ? z : elu(sum_s part[s]) ), vectorized x4 ----
template<int NS>
__global__ __launch_bounds__(256) void expand_x(
    const float* __restrict__ part,   // [NS][B_][HID]
    const float* __restrict__ z,
    _Float16* __restrict__ xn)        // [B_][IN2]
{
  const int idx4 = blockIdx.x * 256 + threadIdx.x;   // B_*IN2/4 exact
  const int b = idx4 / (IN2 / 4), j = (idx4 - b * (IN2 / 4)) * 4;
  half4 o;
  if (j < LAT) {
    f32x4 v = *(const f32x4*)(z + (size_t)b * LAT + j);
    #pragma unroll
    for (int q = 0; q < 4; ++q) o[q] = (_Float16)v[q];
  } else {
    const int h = j - LAT;
    f32x4 v = *(const f32x4*)(part + (size_t)b * HID + h);
    #pragma unroll
    for (int s = 1; s < NS; ++s) {
      f32x4 p = *(const f32x4*)(part + (size_t)s * B_ * HID + (size_t)b * HID + h);
      #pragma unroll
      for (int q = 0; q < 4; ++q) v[q] += p[q];
    }
    #pragma unroll
    for (int q = 0; q < 4; ++q) o[q] = (_Float16)elu(v[q]);
  }
  *(half4*)(xn + (size_t)b * IN2 + j) = o;
}

// ---- final: out = sum_s part[s], vectorized x4 ----
__global__ __launch_bounds__(256) void final_out(
    const float* __restrict__ part,   // [4][B_][FRAME]
    float* __restrict__ out)
{
  const int idx4 = (blockIdx.x * 256 + threadIdx.x) * 4;   // B_*FRAME exact
  f32x4 v = *(const f32x4*)(part + idx4);
  #pragma unroll
  for (int s = 1; s < 4; ++s) {
    f32x4 p = *(const f32x4*)(part + (size_t)s * B_ * FRAME + idx4);
    #pragma unroll
    for (int q = 0; q < 4; ++q) v[q] += p[q];
  }
  *(f32x4*)(out + idx4) = v;
}

// ============================ launch ============================

extern "C" void kernel_launch(void* const* d_in, const int* in_sizes, int n_in,
                              void* d_out, int out_size, void* d_ws, size_t ws_size,
                              hipStream_t stream)
{
  const float* z   = (const float*)d_in[0];
  const float* c   = (const float*)d_in[1];
  const float* w0  = (const float*)d_in[2];
  const float* b0  = (const float*)d_in[3];
  const float* w1  = (const float*)d_in[4];
  const float* b1  = (const float*)d_in[5];
  const float* w2  = (const float*)d_in[6];
  const float* b2  = (const float*)d_in[7];
  const float* gw1 = (const float*)d_in[8];
  const float* gb1 = (const float*)d_in[9];
  const float* gw2 = (const float*)d_in[10];
  const float* gb2 = (const float*)d_in[11];
  const float* gw3 = (const float*)d_in[12];
  const float* gb3 = (const float*)d_in[13];
  float* out = (float*)d_out;
  char* ws = (char*)d_ws;

  // workspace layout (total 121,421,824 < proven 122,814,464).
  // Live-range aliasing: x1 shares x2's slot (x1 dead before expand1 writes x2);
  // Wt0/gw1T/gw2T live above the 64MB part window (dead before gemm L2).
  float*    coef = (float*)    (ws + 0);            //   131,072
  _Float16* x2   = (_Float16*) (ws + 131072);       // 8,912,896  (x1 aliases here)
  _Float16* x1   = (_Float16*) (ws + 131072);       // 4,718,592  (alias)
  _Float16* x3   = (_Float16*) (ws + 9043968);      // 8,912,896
  _Float16* Wt1  = (_Float16*) (ws + 17956864);     // 17,825,792
  _Float16* Wt2  = (_Float16*) (ws + 35782656);     // 8,912,896
  float*    part = (float*)    (ws + 44695552);     // 67,108,864 (window)
  _Float16* Wt0  = (_Float16*) (ws + 111804416);    // 9,437,184
  _Float16* gw1T = (_Float16*) (ws + 121241600);    //   147,456
  _Float16* gw2T = (_Float16*) (ws + 121389056);    //    32,768

  prep_weights<<<4438, 256, 0, stream>>>(w0, w1, w2, gw1, gw2,
                                         Wt0, Wt1, Wt2, gw1T, gw2T);
  gate_mfma<<<64, 256, 0, stream>>>(z, c, gw1T, gw2T, gb1, gb2, gw3, gb3, coef);
  build_x1<<<(B_ * IN1 / 4) / 256, 256, 0, stream>>>(z, c, x1);

  // layer 1: K=576, N=1024, tall 256x128, expert-split 4 x EG2
  gemm_tall<IN1, HID, 2><<<dim3(16, 8, 4), 256, 0, stream>>>(x1, Wt0, coef, b0, part);
  expand_x<4><<<(B_ * IN2 / 4) / 256, 256, 0, stream>>>(part, z, x2);

  // layer 2: K=1088, N=1024, tall 256x128, expert-split 4 x EG2
  gemm_tall<IN2, HID, 2><<<dim3(16, 8, 4), 256, 0, stream>>>(x2, Wt1, coef, b1, part);
  expand_x<4><<<(B_ * IN2 / 4) / 256, 256, 0, stream>>>(part, z, x3);

  // layer 3: K=1088, N=512, 128x128, expert-split 4 x EG2
  gemm_moe<IN2, FRAME, 2><<<dim3(32, 4, 4), 256, 0, stream>>>(x3, Wt2, coef, b2, part);
  final_out<<<(B_ * FRAME / 4) / 256, 256, 0, stream>>>(part, out);
}

// Round 10
// 509.679 us; speedup vs baseline: 1.4389x; 1.4389x over previous
//
#include <hip/hip_runtime.h>
#include <cstdint>
#include <cstddef>

#define B_    4096
#define LAT   64
#define FRAME 512
#define HID   1024
#define NE    8
#define GH    128
#define IN1   576   // LAT + FRAME
#define IN2   1088  // LAT + HID

typedef _Float16 half8 __attribute__((ext_vector_type(8)));
typedef _Float16 half4 __attribute__((ext_vector_type(4)));
typedef float  f32x4  __attribute__((ext_vector_type(4)));

// async global->LDS, 16B per lane; LDS dest = wave-uniform base + lane*16
__device__ inline void async16(const void* g, void* l) {
  __builtin_amdgcn_global_load_lds(
      (__attribute__((address_space(1))) void*)(void*)g,
      (__attribute__((address_space(3))) void*)l, 16, 0, 0);
}

__device__ inline float elu(float v) { return v > 0.f ? v : expm1f(v); }

// ---- unified weight prep: all 5 transpose+casts (fp32 [K][N] -> f16 [N][K]) ----
__global__ __launch_bounds__(256) void prep_weights(
    const float* __restrict__ w0, const float* __restrict__ w1,
    const float* __restrict__ w2, const float* __restrict__ gw1,
    const float* __restrict__ gw2,
    _Float16* __restrict__ Wt0, _Float16* __restrict__ Wt1,
    _Float16* __restrict__ Wt2, _Float16* __restrict__ gw1T,
    _Float16* __restrict__ gw2T)
{
  __shared__ float t[64][65];
  int bid = blockIdx.x;
  const float* in; _Float16* out; int K, N, kt, nt;
  if (bid < 1152) {
    const int e = bid / 144, rem = bid % 144;
    K = IN1; N = HID; kt = rem / 16; nt = rem % 16;
    in = w0 + (size_t)e * K * N; out = Wt0 + (size_t)e * N * K;
  } else if (bid < 3328) {
    const int i = bid - 1152, e = i / 272, rem = i % 272;
    K = IN2; N = HID; kt = rem / 16; nt = rem % 16;
    in = w1 + (size_t)e * K * N; out = Wt1 + (size_t)e * N * K;
  } else if (bid < 4416) {
    const int i = bid - 3328, e = i / 136, rem = i % 136;
    K = IN2; N = FRAME; kt = rem / 8; nt = rem % 8;
    in = w2 + (size_t)e * K * N; out = Wt2 + (size_t)e * N * K;
  } else if (bid < 4434) {
    const int i = bid - 4416;
    K = IN1; N = GH; kt = i / 2; nt = i % 2;
    in = gw1; out = gw1T;
  } else {
    const int i = bid - 4434;
    K = GH; N = GH; kt = i / 2; nt = i % 2;
    in = gw2; out = gw2T;
  }
  const int k0 = kt * 64, n0 = nt * 64;
  const int lr = threadIdx.x >> 4;          // 0..15
  const int lc = (threadIdx.x & 15) * 4;    // 0..60
  #pragma unroll
  for (int rr = 0; rr < 4; ++rr) {
    const int k = rr * 16 + lr;
    f32x4 v = *(const f32x4*)(in + (size_t)(k0 + k) * N + n0 + lc);
    t[k][lc] = v[0]; t[k][lc + 1] = v[1]; t[k][lc + 2] = v[2]; t[k][lc + 3] = v[3];
  }
  __syncthreads();
  #pragma unroll
  for (int rr = 0; rr < 4; ++rr) {
    const int n = rr * 16 + lr;
    half4 o;
    #pragma unroll
    for (int q = 0; q < 4; ++q) o[q] = (_Float16)t[lc + q][n];
    *(half4*)(out + (size_t)(n0 + n) * K + k0 + lc) = o;
  }
}

// ---------------- gate MLP via f16 MFMA -> coef [B, 8] fp32 ----------------
__global__ __launch_bounds__(256) void gate_mfma(
    const float* __restrict__ z, const float* __restrict__ c,
    const _Float16* __restrict__ gw1T,   // [128][576]
    const _Float16* __restrict__ gw2T,   // [128][128]
    const float* __restrict__ gb1, const float* __restrict__ gb2,
    const float* __restrict__ gw3, const float* __restrict__ gb3,
    float* __restrict__ coef)
{
  __shared__ _Float16 h_lds[64][136];
  __shared__ float    h2_lds[64][129];
  __shared__ float    gw3s[128 * 8];
  const int tid = threadIdx.x;
  const int wave = tid >> 6, lane = tid & 63;
  const int quad = lane >> 4, l16 = lane & 15;
  const int r0 = blockIdx.x * 64;

  for (int i = tid; i < 128 * 8; i += 256) gw3s[i] = gw3[i];

  f32x4 acc[8];
  #pragma unroll
  for (int nt = 0; nt < 8; ++nt)
    #pragma unroll
    for (int r = 0; r < 4; ++r) acc[nt][r] = 0.f;

  #pragma unroll 2
  for (int s = 0; s < 18; ++s) {
    const int k0 = s * 32;
    half8 af;
    {
      const size_t row = r0 + wave * 16 + l16;
      const float* src = (k0 < LAT) ? z + row * LAT + k0 + quad * 8
                                    : c + row * FRAME + (k0 - LAT) + quad * 8;
      f32x4 lo = *(const f32x4*)src, hi = *(const f32x4*)(src + 4);
      #pragma unroll
      for (int j = 0; j < 4; ++j) { af[j] = (_Float16)lo[j]; af[j + 4] = (_Float16)hi[j]; }
    }
    half8 bfr[8];
    #pragma unroll
    for (int nt = 0; nt < 8; ++nt)
      bfr[nt] = *(const half8*)(gw1T + (size_t)(nt * 16 + l16) * 576 + k0 + quad * 8);
    #pragma unroll
    for (int nt = 0; nt < 8; ++nt)
      acc[nt] = __builtin_amdgcn_mfma_f32_16x16x32_f16(af, bfr[nt], acc[nt], 0, 0, 0);
  }
  #pragma unroll
  for (int nt = 0; nt < 8; ++nt)
    #pragma unroll
    for (int r = 0; r < 4; ++r) {
      const int rowl = wave * 16 + quad * 4 + r;
      const int col = nt * 16 + l16;
      h_lds[rowl][col] = (_Float16)elu(acc[nt][r] + gb1[col]);
    }
  __syncthreads();

  f32x4 acc2[8];
  #pragma unroll
  for (int nt = 0; nt < 8; ++nt)
    #pragma unroll
    for (int r = 0; r < 4; ++r) acc2[nt][r] = 0.f;
  #pragma unroll
  for (int s = 0; s < 4; ++s) {
    const int k0 = s * 32;
    half8 af = *(const half8*)&h_lds[wave * 16 + l16][k0 + quad * 8];
    half8 bfr[8];
    #pragma unroll
    for (int nt = 0; nt < 8; ++nt)
      bfr[nt] = *(const half8*)(gw2T + (size_t)(nt * 16 + l16) * 128 + k0 + quad * 8);
    #pragma unroll
    for (int nt = 0; nt < 8; ++nt)
      acc2[nt] = __builtin_amdgcn_mfma_f32_16x16x32_f16(af, bfr[nt], acc2[nt], 0, 0, 0);
  }
  #pragma unroll
  for (int nt = 0; nt < 8; ++nt)
    #pragma unroll
    for (int r = 0; r < 4; ++r) {
      const int rowl = wave * 16 + quad * 4 + r;
      const int col = nt * 16 + l16;
      h2_lds[rowl][col] = elu(acc2[nt][r] + gb2[col]);
    }
  __syncthreads();

  {
    const int row = tid >> 2, q = tid & 3;
    float l2v[2] = { gb3[2 * q], gb3[2 * q + 1] };
    for (int k = 0; k < 128; ++k) {
      const float hv = h2_lds[row][k];
      l2v[0] += hv * gw3s[k * 8 + 2 * q];
      l2v[1] += hv * gw3s[k * 8 + 2 * q + 1];
    }
    float m = fmaxf(l2v[0], l2v[1]);
    m = fmaxf(m, __shfl_xor(m, 1));
    m = fmaxf(m, __shfl_xor(m, 2));
    float e0 = expf(l2v[0] - m), e1 = expf(l2v[1] - m);
    float s = e0 + e1;
    s += __shfl_xor(s, 1);
    s += __shfl_xor(s, 2);
    const float inv = 1.f / s;
    float2 o = { e0 * inv, e1 * inv };
    *(float2*)&coef[(size_t)(r0 + row) * NE + 2 * q] = o;
  }
}

// ---- build x1 = [z|c] f16, and z-columns of x2/x3 (gemm writes cols 64+) ----
__global__ __launch_bounds__(256) void build_x(
    const float* __restrict__ z, const float* __restrict__ c,
    _Float16* __restrict__ x1, _Float16* __restrict__ x2,
    _Float16* __restrict__ x3)
{
  const int idx4 = blockIdx.x * 256 + threadIdx.x;   // B_*IN1/4 exact
  const int b = idx4 / (IN1 / 4), j = (idx4 - b * (IN1 / 4)) * 4;
  f32x4 v = (j < LAT) ? *(const f32x4*)(z + (size_t)b * LAT + j)
                      : *(const f32x4*)(c + (size_t)b * FRAME + (j - LAT));
  half4 o;
  #pragma unroll
  for (int q = 0; q < 4; ++q) o[q] = (_Float16)v[q];
  *(half4*)(x1 + (size_t)b * IN1 + j) = o;
  if (j < LAT) {
    *(half4*)(x2 + (size_t)b * IN2 + j) = o;
    *(half4*)(x3 + (size_t)b * IN2 + j) = o;
  }
}

// -------- fused MoE GEMM: A via LDS (dbuf), B direct global->VGPR (dbuf) --------
// All 8 experts per block (EG=8) -> full mixed sum in-register -> fused epilogue:
//   F16OUT: xn[b][LAT+n] = f16(elu(v + coef@bias))   (next layer's input)
//   else  : outf[b][n]   = v + coef@bias             (final fp32 output)
// Tile M=32*MI x N=32*NI, 4 waves (2x2). One barrier per k0 (A dbuf swap).
template<int KDIM, int NOUT, int MI, int NI, bool F16OUT>
__global__ __launch_bounds__(256, 2) void gemm_fused(
    const _Float16* __restrict__ X,     // [B][KDIM]
    const _Float16* __restrict__ Wt,    // [NE][NOUT][KDIM]
    const float* __restrict__ coef,     // [B][8]
    const float* __restrict__ bias,     // [8][NOUT]
    _Float16* __restrict__ xn,          // [B][IN2] (F16OUT)
    float* __restrict__ outf)           // [B][NOUT] (!F16OUT)
{
  constexpr int M = 32 * MI, N = 32 * NI;
  __shared__ __align__(16) _Float16 As[2][M * 64];
  __shared__ float coefS[M * NE];
  __shared__ float biasS[NE * N];

  const int tid = threadIdx.x;
  const int wave = tid >> 6, lane = tid & 63;
  const int wm = wave & 1, wn = wave >> 1;
  const int quad = lane >> 4, l16 = lane & 15;
  const int bm0 = blockIdx.x * M, bn0 = blockIdx.y * N;

  for (int i = tid; i < M * NE; i += 256)
    coefS[i] = coef[(size_t)(bm0 + (i >> 3)) * NE + (i & 7)];
  for (int i = tid; i < NE * N; i += 256)
    biasS[i] = bias[(size_t)(i / N) * NOUT + bn0 + (i % N)];

  const int srow  = wave * 8 + (lane >> 3);                  // + it*32
  const int skoff = (((lane & 7) ^ ((lane >> 3) & 7)) * 8);  // A-staging swizzle

  // per-lane B row offsets (elements, 32-bit safe: max ~9M elems)
  int rowoff[NI];
  #pragma unroll
  for (int ni = 0; ni < NI; ++ni)
    rowoff[ni] = (bn0 + wn * 16 * NI + ni * 16 + l16) * KDIM;
  const int koffB = quad * 8;

  #define STAGE_A(k0v, buf) \
    { _Pragma("unroll") \
      for (int it = 0; it < MI; ++it) \
        async16(X + (size_t)(bm0 + it * 32 + srow) * KDIM + (k0v) + skoff, \
                &(buf)[it * 2048 + wave * 512]); }

  half8 bv[2][2 * NI];
  auto loadB = [&](int e, int k0v, half8* dst) {
    const _Float16* p = Wt + (size_t)e * NOUT * KDIM + k0v + koffB;
    #pragma unroll
    for (int ks = 0; ks < 2; ++ks)
      #pragma unroll
      for (int ni = 0; ni < NI; ++ni)
        dst[ks * NI + ni] = *(const half8*)(p + rowoff[ni] + ks * 32);
  };

  STAGE_A(0, As[0]);
  loadB(0, 0, bv[0]);
  __syncthreads();   // coefS/biasS ready + As[0] DMA drained

  // per-lane coef for A-scaling: A-fragment row = wm*16*MI + mi*16 + l16
  _Float16 ch[MI][NE];
  #pragma unroll
  for (int mi = 0; mi < MI; ++mi)
    #pragma unroll
    for (int e = 0; e < NE; ++e)
      ch[mi][e] = (_Float16)coefS[(wm * 16 * MI + mi * 16 + l16) * NE + e];

  f32x4 acc[MI][NI];
  #pragma unroll
  for (int mi = 0; mi < MI; ++mi)
    #pragma unroll
    for (int ni = 0; ni < NI; ++ni)
      #pragma unroll
      for (int r = 0; r < 4; ++r) acc[mi][ni][r] = 0.f;

  constexpr int K0S = KDIM / 64;
  for (int k0i = 0; k0i < K0S; ++k0i) {
    const int k0 = k0i * 64, ap = k0i & 1;
    // A fragments for this k0 (reused across all 8 experts)
    half8 af[2][MI];
    #pragma unroll
    for (int ks = 0; ks < 2; ++ks)
      #pragma unroll
      for (int mi = 0; mi < MI; ++mi) {
        const int r = wm * 16 * MI + mi * 16 + l16;
        const int g = (ks * 4 + quad) ^ (r & 7);
        af[ks][mi] = *(const half8*)&As[ap][r * 64 + g * 8];
      }
    if (k0i + 1 < K0S) STAGE_A(k0 + 64, As[1 - ap]);   // into other buffer

    #pragma unroll
    for (int eo = 0; eo < NE; ++eo) {
      if (eo + 1 < NE)           loadB(eo + 1, k0, bv[(eo + 1) & 1]);
      else if (k0i + 1 < K0S)    loadB(0, k0 + 64, bv[0]);
      const half8* bq = bv[eo & 1];
      #pragma unroll
      for (int ks = 0; ks < 2; ++ks)
        #pragma unroll
        for (int mi = 0; mi < MI; ++mi) {
          const half8 afs = af[ks][mi] * ch[mi][eo];
          #pragma unroll
          for (int ni = 0; ni < NI; ++ni)
            acc[mi][ni] = __builtin_amdgcn_mfma_f32_16x16x32_f16(
                afs, bq[ks * NI + ni], acc[mi][ni], 0, 0, 0);
        }
    }
    __syncthreads();   // all af reads done + next-A DMA drained -> safe buffer swap
  }
  #undef STAGE_A

  // fused epilogue (full expert sum is local): + coef@bias, ELU+f16 or fp32
  #pragma unroll
  for (int mi = 0; mi < MI; ++mi)
    #pragma unroll
    for (int r = 0; r < 4; ++r) {
      const int m_loc = wm * 16 * MI + mi * 16 + quad * 4 + r;
      const size_t grow = (size_t)(bm0 + m_loc);
      #pragma unroll
      for (int ni = 0; ni < NI; ++ni) {
        const int n_loc = wn * 16 * NI + ni * 16 + l16;
        float v = acc[mi][ni][r];
        #pragma unroll
        for (int e = 0; e < NE; ++e)
          v += coefS[m_loc * NE + e] * biasS[e * N + n_loc];
        if (F16OUT) xn[grow * IN2 + LAT + bn0 + n_loc] = (_Float16)elu(v);
        else        outf[grow * NOUT + bn0 + n_loc] = v;
      }
    }
}

// ============================ launch ============================

extern "C" void kernel_launch(void* const* d_in, const int* in_sizes, int n_in,
                              void* d_out, int out_size, void* d_ws, size_t ws_size,
                              hipStream_t stream)
{
  const float* z   = (const float*)d_in[0];
  const float* c   = (const float*)d_in[1];
  const float* w0  = (const float*)d_in[2];
  const float* b0  = (const float*)d_in[3];
  const float* w1  = (const float*)d_in[4];
  const float* b1  = (const float*)d_in[5];
  const float* w2  = (const float*)d_in[6];
  const float* b2  = (const float*)d_in[7];
  const float* gw1 = (const float*)d_in[8];
  const float* gb1 = (const float*)d_in[9];
  const float* gw2 = (const float*)d_in[10];
  const float* gb2 = (const float*)d_in[11];
  const float* gw3 = (const float*)d_in[12];
  const float* gb3 = (const float*)d_in[13];
  float* out = (float*)d_out;
  char* ws = (char*)d_ws;

  // workspace layout, total 59,031,552 bytes (< proven 122,814,464)
  float*    coef = (float*)    (ws + 0);           //   131,072
  _Float16* x1   = (_Float16*) (ws + 131072);      // 4,718,592
  _Float16* x2   = (_Float16*) (ws + 4849664);     // 8,912,896
  _Float16* x3   = (_Float16*) (ws + 13762560);    // 8,912,896
  _Float16* Wt0  = (_Float16*) (ws + 22675456);    // 9,437,184
  _Float16* Wt1  = (_Float16*) (ws + 32112640);    // 17,825,792
  _Float16* Wt2  = (_Float16*) (ws + 49938432);    // 8,912,896
  _Float16* gw1T = (_Float16*) (ws + 58851328);    //   147,456
  _Float16* gw2T = (_Float16*) (ws + 58998784);    //    32,768

  prep_weights<<<4438, 256, 0, stream>>>(w0, w1, w2, gw1, gw2,
                                         Wt0, Wt1, Wt2, gw1T, gw2T);
  gate_mfma<<<64, 256, 0, stream>>>(z, c, gw1T, gw2T, gb1, gb2, gw3, gb3, coef);
  build_x<<<(B_ * IN1 / 4) / 256, 256, 0, stream>>>(z, c, x1, x2, x3);

  // layer 1: K=576, N=1024, tile 128x64, grid 32x16=512, all 8 experts/block
  gemm_fused<IN1, HID, 4, 2, true><<<dim3(32, 16), 256, 0, stream>>>(
      x1, Wt0, coef, b0, x2, nullptr);
  // layer 2: K=1088, N=1024, tile 128x64, grid 32x16=512
  gemm_fused<IN2, HID, 4, 2, true><<<dim3(32, 16), 256, 0, stream>>>(
      x2, Wt1, coef, b1, x3, nullptr);
  // layer 3: K=1088, N=512, tile 64x64, grid 64x8=512, fp32 direct out
  gemm_fused<IN2, FRAME, 2, 2, false><<<dim3(64, 8), 256, 0, stream>>>(
      x3, Wt2, coef, b2, nullptr, out);
}

// Round 11
// 366.267 us; speedup vs baseline: 2.0023x; 1.3916x over previous
//
#include <hip/hip_runtime.h>
#include <cstdint>
#include <cstddef>

#define B_    4096
#define LAT   64
#define FRAME 512
#define HID   1024
#define NE    8
#define GH    128
#define IN1   576   // LAT + FRAME
#define IN2   1088  // LAT + HID

typedef _Float16 half8 __attribute__((ext_vector_type(8)));
typedef _Float16 half4 __attribute__((ext_vector_type(4)));
typedef float  f32x4  __attribute__((ext_vector_type(4)));

// async global->LDS, 16B per lane; LDS dest = wave-uniform base + lane*16
__device__ inline void async16(const void* g, void* l) {
  __builtin_amdgcn_global_load_lds(
      (__attribute__((address_space(1))) void*)(void*)g,
      (__attribute__((address_space(3))) void*)l, 16, 0, 0);
}

__device__ inline float elu(float v) { return v > 0.f ? v : expm1f(v); }

// ---- unified weight prep: all 5 transpose+casts (fp32 [K][N] -> f16 [N][K]) ----
__global__ __launch_bounds__(256) void prep_weights(
    const float* __restrict__ w0, const float* __restrict__ w1,
    const float* __restrict__ w2, const float* __restrict__ gw1,
    const float* __restrict__ gw2,
    _Float16* __restrict__ Wt0, _Float16* __restrict__ Wt1,
    _Float16* __restrict__ Wt2, _Float16* __restrict__ gw1T,
    _Float16* __restrict__ gw2T)
{
  __shared__ float t[64][65];
  int bid = blockIdx.x;
  const float* in; _Float16* out; int K, N, kt, nt;
  if (bid < 1152) {
    const int e = bid / 144, rem = bid % 144;
    K = IN1; N = HID; kt = rem / 16; nt = rem % 16;
    in = w0 + (size_t)e * K * N; out = Wt0 + (size_t)e * N * K;
  } else if (bid < 3328) {
    const int i = bid - 1152, e = i / 272, rem = i % 272;
    K = IN2; N = HID; kt = rem / 16; nt = rem % 16;
    in = w1 + (size_t)e * K * N; out = Wt1 + (size_t)e * N * K;
  } else if (bid < 4416) {
    const int i = bid - 3328, e = i / 136, rem = i % 136;
    K = IN2; N = FRAME; kt = rem / 8; nt = rem % 8;
    in = w2 + (size_t)e * K * N; out = Wt2 + (size_t)e * N * K;
  } else if (bid < 4434) {
    const int i = bid - 4416;
    K = IN1; N = GH; kt = i / 2; nt = i % 2;
    in = gw1; out = gw1T;
  } else {
    const int i = bid - 4434;
    K = GH; N = GH; kt = i / 2; nt = i % 2;
    in = gw2; out = gw2T;
  }
  const int k0 = kt * 64, n0 = nt * 64;
  const int lr = threadIdx.x >> 4;          // 0..15
  const int lc = (threadIdx.x & 15) * 4;    // 0..60
  #pragma unroll
  for (int rr = 0; rr < 4; ++rr) {
    const int k = rr * 16 + lr;
    f32x4 v = *(const f32x4*)(in + (size_t)(k0 + k) * N + n0 + lc);
    t[k][lc] = v[0]; t[k][lc + 1] = v[1]; t[k][lc + 2] = v[2]; t[k][lc + 3] = v[3];
  }
  __syncthreads();
  #pragma unroll
  for (int rr = 0; rr < 4; ++rr) {
    const int n = rr * 16 + lr;
    half4 o;
    #pragma unroll
    for (int q = 0; q < 4; ++q) o[q] = (_Float16)t[lc + q][n];
    *(half4*)(out + (size_t)(n0 + n) * K + k0 + lc) = o;
  }
}

// ---------------- gate MLP via f16 MFMA -> coef [B, 8] fp32 ----------------
__global__ __launch_bounds__(256) void gate_mfma(
    const float* __restrict__ z, const float* __restrict__ c,
    const _Float16* __restrict__ gw1T,   // [128][576]
    const _Float16* __restrict__ gw2T,   // [128][128]
    const float* __restrict__ gb1, const float* __restrict__ gb2,
    const float* __restrict__ gw3, const float* __restrict__ gb3,
    float* __restrict__ coef)
{
  __shared__ _Float16 h_lds[64][136];
  __shared__ float    h2_lds[64][129];
  __shared__ float    gw3s[128 * 8];
  const int tid = threadIdx.x;
  const int wave = tid >> 6, lane = tid & 63;
  const int quad = lane >> 4, l16 = lane & 15;
  const int r0 = blockIdx.x * 64;

  for (int i = tid; i < 128 * 8; i += 256) gw3s[i] = gw3[i];

  f32x4 acc[8];
  #pragma unroll
  for (int nt = 0; nt < 8; ++nt)
    #pragma unroll
    for (int r = 0; r < 4; ++r) acc[nt][r] = 0.f;

  #pragma unroll 2
  for (int s = 0; s < 18; ++s) {
    const int k0 = s * 32;
    half8 af;
    {
      const size_t row = r0 + wave * 16 + l16;
      const float* src = (k0 < LAT) ? z + row * LAT + k0 + quad * 8
                                    : c + row * FRAME + (k0 - LAT) + quad * 8;
      f32x4 lo = *(const f32x4*)src, hi = *(const f32x4*)(src + 4);
      #pragma unroll
      for (int j = 0; j < 4; ++j) { af[j] = (_Float16)lo[j]; af[j + 4] = (_Float16)hi[j]; }
    }
    half8 bfr[8];
    #pragma unroll
    for (int nt = 0; nt < 8; ++nt)
      bfr[nt] = *(const half8*)(gw1T + (size_t)(nt * 16 + l16) * 576 + k0 + quad * 8);
    #pragma unroll
    for (int nt = 0; nt < 8; ++nt)
      acc[nt] = __builtin_amdgcn_mfma_f32_16x16x32_f16(af, bfr[nt], acc[nt], 0, 0, 0);
  }
  #pragma unroll
  for (int nt = 0; nt < 8; ++nt)
    #pragma unroll
    for (int r = 0; r < 4; ++r) {
      const int rowl = wave * 16 + quad * 4 + r;
      const int col = nt * 16 + l16;
      h_lds[rowl][col] = (_Float16)elu(acc[nt][r] + gb1[col]);
    }
  __syncthreads();

  f32x4 acc2[8];
  #pragma unroll
  for (int nt = 0; nt < 8; ++nt)
    #pragma unroll
    for (int r = 0; r < 4; ++r) acc2[nt][r] = 0.f;
  #pragma unroll
  for (int s = 0; s < 4; ++s) {
    const int k0 = s * 32;
    half8 af = *(const half8*)&h_lds[wave * 16 + l16][k0 + quad * 8];
    half8 bfr[8];
    #pragma unroll
    for (int nt = 0; nt < 8; ++nt)
      bfr[nt] = *(const half8*)(gw2T + (size_t)(nt * 16 + l16) * 128 + k0 + quad * 8);
    #pragma unroll
    for (int nt = 0; nt < 8; ++nt)
      acc2[nt] = __builtin_amdgcn_mfma_f32_16x16x32_f16(af, bfr[nt], acc2[nt], 0, 0, 0);
  }
  #pragma unroll
  for (int nt = 0; nt < 8; ++nt)
    #pragma unroll
    for (int r = 0; r < 4; ++r) {
      const int rowl = wave * 16 + quad * 4 + r;
      const int col = nt * 16 + l16;
      h2_lds[rowl][col] = elu(acc2[nt][r] + gb2[col]);
    }
  __syncthreads();

  {
    const int row = tid >> 2, q = tid & 3;
    float l2v[2] = { gb3[2 * q], gb3[2 * q + 1] };
    for (int k = 0; k < 128; ++k) {
      const float hv = h2_lds[row][k];
      l2v[0] += hv * gw3s[k * 8 + 2 * q];
      l2v[1] += hv * gw3s[k * 8 + 2 * q + 1];
    }
    float m = fmaxf(l2v[0], l2v[1]);
    m = fmaxf(m, __shfl_xor(m, 1));
    m = fmaxf(m, __shfl_xor(m, 2));
    float e0 = expf(l2v[0] - m), e1 = expf(l2v[1] - m);
    float s = e0 + e1;
    s += __shfl_xor(s, 1);
    s += __shfl_xor(s, 2);
    const float inv = 1.f / s;
    float2 o = { e0 * inv, e1 * inv };
    *(float2*)&coef[(size_t)(r0 + row) * NE + 2 * q] = o;
  }
}

// ---- build x1 = [z|c] f16, and z-columns of x2/x3 (gemm writes cols 64+) ----
__global__ __launch_bounds__(256) void build_x(
    const float* __restrict__ z, const float* __restrict__ c,
    _Float16* __restrict__ x1, _Float16* __restrict__ x2,
    _Float16* __restrict__ x3)
{
  const int idx4 = blockIdx.x * 256 + threadIdx.x;   // B_*IN1/4 exact
  const int b = idx4 / (IN1 / 4), j = (idx4 - b * (IN1 / 4)) * 4;
  f32x4 v = (j < LAT) ? *(const f32x4*)(z + (size_t)b * LAT + j)
                      : *(const f32x4*)(c + (size_t)b * FRAME + (j - LAT));
  half4 o;
  #pragma unroll
  for (int q = 0; q < 4; ++q) o[q] = (_Float16)v[q];
  *(half4*)(x1 + (size_t)b * IN1 + j) = o;
  if (j < LAT) {
    *(half4*)(x2 + (size_t)b * IN2 + j) = o;
    *(half4*)(x3 + (size_t)b * IN2 + j) = o;
  }
}

// ---- fused MoE GEMM, r8-verified K-loop: tile 128x64, ALL 8 experts/block ----
// A staged once per k0 (reused across 8 experts); B LDS double-buffered.
// Full mixed sum block-local -> fused epilogue: xn = f16(elu(v + coef@bias)).
template<int KDIM, int NOUT>
__global__ __launch_bounds__(256, 2) void gemm_fused(
    const _Float16* __restrict__ X,     // [B][KDIM]
    const _Float16* __restrict__ Wt,    // [NE][NOUT][KDIM]
    const float* __restrict__ coef,     // [B][8]
    const float* __restrict__ bias,     // [8][NOUT]
    _Float16* __restrict__ xn)          // [B][IN2], cols 64+
{
  __shared__ __align__(16) _Float16 As[128 * 64];
  __shared__ __align__(16) _Float16 Bs[2][64 * 64];
  __shared__ float coefS[128 * NE];
  __shared__ float biasS[NE * 64];

  const int tid = threadIdx.x;
  const int wave = tid >> 6, lane = tid & 63;
  const int wm = wave & 1, wn = wave >> 1;
  const int quad = lane >> 4, l16 = lane & 15;
  const int bm0 = blockIdx.x * 128, bn0 = blockIdx.y * 64;

  for (int i = tid; i < 128 * NE; i += 256)
    coefS[i] = coef[(size_t)(bm0 + (i >> 3)) * NE + (i & 7)];
  for (int i = tid; i < NE * 64; i += 256)
    biasS[i] = bias[(size_t)(i >> 6) * NOUT + bn0 + (i & 63)];
  __syncthreads();

  // per-lane coef for A-scaling: A-fragment row = wm*64 + mi*16 + l16
  _Float16 ch[4][NE];
  #pragma unroll
  for (int mi = 0; mi < 4; ++mi)
    #pragma unroll
    for (int e = 0; e < NE; ++e)
      ch[mi][e] = (_Float16)coefS[(wm * 64 + mi * 16 + l16) * NE + e];

  f32x4 acc[4][2];
  #pragma unroll
  for (int mi = 0; mi < 4; ++mi)
    #pragma unroll
    for (int ni = 0; ni < 2; ++ni)
      #pragma unroll
      for (int r = 0; r < 4; ++r) acc[mi][ni][r] = 0.f;

  const int srow  = wave * 8 + (lane >> 3);                  // + it*32
  const int skoff = (((lane & 7) ^ ((lane >> 3) & 7)) * 8);  // swizzled src granule

  constexpr int K0S = KDIM / 64;
  for (int k0i = 0; k0i < K0S; ++k0i) {
    const int k0 = k0i * 64;
    // stage A (once per k0) and expert 0's B
    #pragma unroll
    for (int it = 0; it < 4; ++it)
      async16(X + (size_t)(bm0 + it * 32 + srow) * KDIM + k0 + skoff,
              &As[it * 2048 + wave * 512]);
    #pragma unroll
    for (int it = 0; it < 2; ++it)
      async16(Wt + (size_t)(bn0 + it * 32 + srow) * KDIM + k0 + skoff,
              &Bs[0][it * 2048 + wave * 512]);
    __syncthreads();

    // A fragments for this k0, reused across all 8 experts
    half8 af[2][4];
    #pragma unroll
    for (int ks = 0; ks < 2; ++ks)
      #pragma unroll
      for (int mi = 0; mi < 4; ++mi) {
        const int r = wm * 64 + mi * 16 + l16;
        const int g = (ks * 4 + quad) ^ (r & 7);
        af[ks][mi] = *(const half8*)&As[r * 64 + g * 8];
      }

    #pragma unroll
    for (int eo = 0; eo < NE; ++eo) {
      if (eo + 1 < NE) {   // prefetch next expert's B into other buffer
        const size_t eoff = (size_t)(eo + 1) * NOUT * KDIM;
        #pragma unroll
        for (int it = 0; it < 2; ++it)
          async16(Wt + eoff + (size_t)(bn0 + it * 32 + srow) * KDIM + k0 + skoff,
                  &Bs[(eo + 1) & 1][it * 2048 + wave * 512]);
      }
      const _Float16* bsrc = Bs[eo & 1];
      #pragma unroll
      for (int ks = 0; ks < 2; ++ks) {
        half8 bv[2];
        #pragma unroll
        for (int ni = 0; ni < 2; ++ni) {
          const int r = wn * 32 + ni * 16 + l16;
          const int g = (ks * 4 + quad) ^ (r & 7);
          bv[ni] = *(const half8*)&bsrc[r * 64 + g * 8];
        }
        #pragma unroll
        for (int mi = 0; mi < 4; ++mi) {
          const half8 afs = af[ks][mi] * ch[mi][eo];
          #pragma unroll
          for (int ni = 0; ni < 2; ++ni)
            acc[mi][ni] = __builtin_amdgcn_mfma_f32_16x16x32_f16(
                afs, bv[ni], acc[mi][ni], 0, 0, 0);
        }
      }
      __syncthreads();   // protects Bs reuse and As for next k0's staging
    }
  }

  // fused epilogue: + coef@bias, ELU, f16 into next layer's input
  #pragma unroll
  for (int mi = 0; mi < 4; ++mi)
    #pragma unroll
    for (int r = 0; r < 4; ++r) {
      const int m_loc = wm * 64 + mi * 16 + quad * 4 + r;
      const size_t grow = (size_t)(bm0 + m_loc);
      #pragma unroll
      for (int ni = 0; ni < 2; ++ni) {
        const int n_loc = wn * 32 + ni * 16 + l16;
        float v = acc[mi][ni][r];
        #pragma unroll
        for (int e = 0; e < NE; ++e)
          v += coefS[m_loc * NE + e] * biasS[e * 64 + n_loc];
        xn[grow * IN2 + LAT + bn0 + n_loc] = (_Float16)elu(v);
      }
    }
}

// -------- 128x128 MoE GEMM (r8-verified), layer 3 -> fp32 partials --------
template<int KDIM, int NOUT, int EG>
__global__ __launch_bounds__(256, 2) void gemm_moe(
    const _Float16* __restrict__ X,
    const _Float16* __restrict__ Wt,
    const float* __restrict__ coef,
    const float* __restrict__ bias,
    float* __restrict__ part)
{
  __shared__ __align__(16) _Float16 As[128 * 64];
  __shared__ __align__(16) _Float16 Bs[2][128 * 64];
  __shared__ float coefS[128 * EG];
  __shared__ float biasS[EG * 128];

  const int tid = threadIdx.x;
  const int wave = tid >> 6, lane = tid & 63;
  const int wm = wave & 1, wn = wave >> 1;
  const int quad = lane >> 4, l16 = lane & 15;
  const int bm0 = blockIdx.x * 128, bn0 = blockIdx.y * 128;
  const int ebase = blockIdx.z * EG;

  for (int i = tid; i < 128 * EG; i += 256)
    coefS[i] = coef[(size_t)(bm0 + i / EG) * NE + ebase + (i % EG)];
  for (int i = tid; i < EG * 128; i += 256)
    biasS[i] = bias[(size_t)(ebase + (i >> 7)) * NOUT + bn0 + (i & 127)];
  __syncthreads();

  _Float16 ch[4][EG];
  #pragma unroll
  for (int mi = 0; mi < 4; ++mi)
    #pragma unroll
    for (int e = 0; e < EG; ++e)
      ch[mi][e] = (_Float16)coefS[(wm * 64 + mi * 16 + l16) * EG + e];

  f32x4 acc[4][4];
  #pragma unroll
  for (int mi = 0; mi < 4; ++mi)
    #pragma unroll
    for (int ni = 0; ni < 4; ++ni)
      #pragma unroll
      for (int r = 0; r < 4; ++r) acc[mi][ni][r] = 0.f;

  const int srow  = wave * 8 + (lane >> 3);
  const int skoff = (((lane & 7) ^ ((lane >> 3) & 7)) * 8);

  constexpr int K0S = KDIM / 64;
  for (int k0i = 0; k0i < K0S; ++k0i) {
    const int k0 = k0i * 64;
    #pragma unroll
    for (int it = 0; it < 4; ++it)
      async16(X + (size_t)(bm0 + it * 32 + srow) * KDIM + k0 + skoff,
              &As[it * 2048 + wave * 512]);
    {
      const size_t eoff = (size_t)ebase * NOUT * KDIM;
      #pragma unroll
      for (int it = 0; it < 4; ++it)
        async16(Wt + eoff + (size_t)(bn0 + it * 32 + srow) * KDIM + k0 + skoff,
                &Bs[0][it * 2048 + wave * 512]);
    }
    __syncthreads();

    half8 af[2][4];
    #pragma unroll
    for (int ks = 0; ks < 2; ++ks)
      #pragma unroll
      for (int mi = 0; mi < 4; ++mi) {
        const int r = wm * 64 + mi * 16 + l16;
        const int g = (ks * 4 + quad) ^ (r & 7);
        af[ks][mi] = *(const half8*)&As[r * 64 + g * 8];
      }

    #pragma unroll
    for (int eo = 0; eo < EG; ++eo) {
      if (eo + 1 < EG) {
        const size_t eoff = (size_t)(ebase + eo + 1) * NOUT * KDIM;
        #pragma unroll
        for (int it = 0; it < 4; ++it)
          async16(Wt + eoff + (size_t)(bn0 + it * 32 + srow) * KDIM + k0 + skoff,
                  &Bs[(eo + 1) & 1][it * 2048 + wave * 512]);
      }
      const _Float16* bsrc = Bs[eo & 1];
      #pragma unroll
      for (int ks = 0; ks < 2; ++ks) {
        half8 bv[4];
        #pragma unroll
        for (int ni = 0; ni < 4; ++ni) {
          const int r = wn * 64 + ni * 16 + l16;
          const int g = (ks * 4 + quad) ^ (r & 7);
          bv[ni] = *(const half8*)&bsrc[r * 64 + g * 8];
        }
        #pragma unroll
        for (int mi = 0; mi < 4; ++mi) {
          const half8 afs = af[ks][mi] * ch[mi][eo];
          #pragma unroll
          for (int ni = 0; ni < 4; ++ni)
            acc[mi][ni] = __builtin_amdgcn_mfma_f32_16x16x32_f16(
                afs, bv[ni], acc[mi][ni], 0, 0, 0);
        }
      }
      __syncthreads();
    }
  }

  float* po = part + (size_t)blockIdx.z * B_ * NOUT;
  #pragma unroll
  for (int mi = 0; mi < 4; ++mi)
    #pragma unroll
    for (int r = 0; r < 4; ++r) {
      const int m_loc = wm * 64 + mi * 16 + quad * 4 + r;
      #pragma unroll
      for (int ni = 0; ni < 4; ++ni) {
        const int n_loc = wn * 64 + ni * 16 + l16;
        float v = acc[mi][ni][r];
        #pragma unroll
        for (int e = 0; e < EG; ++e)
          v += coefS[m_loc * EG + e] * biasS[e * 128 + n_loc];
        po[(size_t)(bm0 + m_loc) * NOUT + bn0 + n_loc] = v;
      }
    }
}

// ---- final: out = sum_s part[s], vectorized x4 ----
__global__ __launch_bounds__(256) void final_out(
    const float* __restrict__ part,   // [4][B_][FRAME]
    float* __restrict__ out)
{
  const int idx4 = (blockIdx.x * 256 + threadIdx.x) * 4;   // B_*FRAME exact
  f32x4 v = *(const f32x4*)(part + idx4);
  #pragma unroll
  for (int s = 1; s < 4; ++s) {
    f32x4 p = *(const f32x4*)(part + (size_t)s * B_ * FRAME + idx4);
    #pragma unroll
    for (int q = 0; q < 4; ++q) v[q] += p[q];
  }
  *(f32x4*)(out + idx4) = v;
}

// ============================ launch ============================

extern "C" void kernel_launch(void* const* d_in, const int* in_sizes, int n_in,
                              void* d_out, int out_size, void* d_ws, size_t ws_size,
                              hipStream_t stream)
{
  const float* z   = (const float*)d_in[0];
  const float* c   = (const float*)d_in[1];
  const float* w0  = (const float*)d_in[2];
  const float* b0  = (const float*)d_in[3];
  const float* w1  = (const float*)d_in[4];
  const float* b1  = (const float*)d_in[5];
  const float* w2  = (const float*)d_in[6];
  const float* b2  = (const float*)d_in[7];
  const float* gw1 = (const float*)d_in[8];
  const float* gb1 = (const float*)d_in[9];
  const float* gw2 = (const float*)d_in[10];
  const float* gb2 = (const float*)d_in[11];
  const float* gw3 = (const float*)d_in[12];
  const float* gb3 = (const float*)d_in[13];
  float* out = (float*)d_out;
  char* ws = (char*)d_ws;

  // workspace layout, total 92,585,984 bytes (< proven 122,814,464)
  float*    coef = (float*)    (ws + 0);           //   131,072
  _Float16* x1   = (_Float16*) (ws + 131072);      // 4,718,592
  _Float16* x2   = (_Float16*) (ws + 4849664);     // 8,912,896
  _Float16* x3   = (_Float16*) (ws + 13762560);    // 8,912,896
  _Float16* Wt0  = (_Float16*) (ws + 22675456);    // 9,437,184
  _Float16* Wt1  = (_Float16*) (ws + 32112640);    // 17,825,792
  _Float16* Wt2  = (_Float16*) (ws + 49938432);    // 8,912,896
  float*    part = (float*)    (ws + 58851328);    // 33,554,432
  _Float16* gw1T = (_Float16*) (ws + 92405760);    //   147,456
  _Float16* gw2T = (_Float16*) (ws + 92553216);    //    32,768

  prep_weights<<<4438, 256, 0, stream>>>(w0, w1, w2, gw1, gw2,
                                         Wt0, Wt1, Wt2, gw1T, gw2T);
  gate_mfma<<<64, 256, 0, stream>>>(z, c, gw1T, gw2T, gb1, gb2, gw3, gb3, coef);
  build_x<<<(B_ * IN1 / 4) / 256, 256, 0, stream>>>(z, c, x1, x2, x3);

  // layer 1: K=576, N=1024, tile 128x64, all 8 experts/block, fused epilogue
  gemm_fused<IN1, HID><<<dim3(32, 16), 256, 0, stream>>>(x1, Wt0, coef, b0, x2);
  // layer 2: K=1088, N=1024, tile 128x64, fused epilogue
  gemm_fused<IN2, HID><<<dim3(32, 16), 256, 0, stream>>>(x2, Wt1, coef, b1, x3);
  // layer 3: K=1088, N=512, 128x128, expert-split 4 x EG2 -> partials + final
  gemm_moe<IN2, FRAME, 2><<<dim3(32, 4, 4), 256, 0, stream>>>(x3, Wt2, coef, b2, part);
  final_out<<<(B_ * FRAME / 4) / 256, 256, 0, stream>>>(part, out);
}

// Round 12
// 341.656 us; speedup vs baseline: 2.1465x; 1.0720x over previous
//
#include <hip/hip_runtime.h>
#include <cstdint>
#include <cstddef>

#define B_    4096
#define LAT   64
#define FRAME 512
#define HID   1024
#define NE    8
#define GH    128
#define IN1   576   // LAT + FRAME
#define IN2   1088  // LAT + HID

typedef _Float16 half8 __attribute__((ext_vector_type(8)));
typedef _Float16 half4 __attribute__((ext_vector_type(4)));
typedef float  f32x4  __attribute__((ext_vector_type(4)));

// async global->LDS, 16B per lane; LDS dest = wave-uniform base + lane*16
__device__ inline void async16(const void* g, void* l) {
  __builtin_amdgcn_global_load_lds(
      (__attribute__((address_space(1))) void*)(void*)g,
      (__attribute__((address_space(3))) void*)l, 16, 0, 0);
}

__device__ inline float elu(float v) { return v > 0.f ? v : expm1f(v); }

// ---- unified prep: 5 weight transpose+casts (fp32 [K][N] -> f16 [N][K])
//      + build x1=[z|c] f16 and z-cols of x2/x3 (blocks 4438+) ----
__global__ __launch_bounds__(256) void prep_weights(
    const float* __restrict__ w0, const float* __restrict__ w1,
    const float* __restrict__ w2, const float* __restrict__ gw1,
    const float* __restrict__ gw2,
    const float* __restrict__ z,  const float* __restrict__ c,
    _Float16* __restrict__ Wt0, _Float16* __restrict__ Wt1,
    _Float16* __restrict__ Wt2, _Float16* __restrict__ gw1T,
    _Float16* __restrict__ gw2T,
    _Float16* __restrict__ x1, _Float16* __restrict__ x2,
    _Float16* __restrict__ x3)
{
  __shared__ float t[64][65];
  int bid = blockIdx.x;
  if (bid >= 4438) {   // build_x part: 2304 blocks, vectorized x4
    const int idx4 = (bid - 4438) * 256 + threadIdx.x;   // B_*IN1/4 exact
    const int b = idx4 / (IN1 / 4), j = (idx4 - b * (IN1 / 4)) * 4;
    f32x4 v = (j < LAT) ? *(const f32x4*)(z + (size_t)b * LAT + j)
                        : *(const f32x4*)(c + (size_t)b * FRAME + (j - LAT));
    half4 o;
    #pragma unroll
    for (int q = 0; q < 4; ++q) o[q] = (_Float16)v[q];
    *(half4*)(x1 + (size_t)b * IN1 + j) = o;
    if (j < LAT) {
      *(half4*)(x2 + (size_t)b * IN2 + j) = o;
      *(half4*)(x3 + (size_t)b * IN2 + j) = o;
    }
    return;
  }
  const float* in; _Float16* out; int K, N, kt, nt;
  if (bid < 1152) {
    const int e = bid / 144, rem = bid % 144;
    K = IN1; N = HID; kt = rem / 16; nt = rem % 16;
    in = w0 + (size_t)e * K * N; out = Wt0 + (size_t)e * N * K;
  } else if (bid < 3328) {
    const int i = bid - 1152, e = i / 272, rem = i % 272;
    K = IN2; N = HID; kt = rem / 16; nt = rem % 16;
    in = w1 + (size_t)e * K * N; out = Wt1 + (size_t)e * N * K;
  } else if (bid < 4416) {
    const int i = bid - 3328, e = i / 136, rem = i % 136;
    K = IN2; N = FRAME; kt = rem / 8; nt = rem % 8;
    in = w2 + (size_t)e * K * N; out = Wt2 + (size_t)e * N * K;
  } else if (bid < 4434) {
    const int i = bid - 4416;
    K = IN1; N = GH; kt = i / 2; nt = i % 2;
    in = gw1; out = gw1T;
  } else {
    const int i = bid - 4434;
    K = GH; N = GH; kt = i / 2; nt = i % 2;
    in = gw2; out = gw2T;
  }
  const int k0 = kt * 64, n0 = nt * 64;
  const int lr = threadIdx.x >> 4;          // 0..15
  const int lc = (threadIdx.x & 15) * 4;    // 0..60
  #pragma unroll
  for (int rr = 0; rr < 4; ++rr) {
    const int k = rr * 16 + lr;
    f32x4 v = *(const f32x4*)(in + (size_t)(k0 + k) * N + n0 + lc);
    t[k][lc] = v[0]; t[k][lc + 1] = v[1]; t[k][lc + 2] = v[2]; t[k][lc + 3] = v[3];
  }
  __syncthreads();
  #pragma unroll
  for (int rr = 0; rr < 4; ++rr) {
    const int n = rr * 16 + lr;
    half4 o;
    #pragma unroll
    for (int q = 0; q < 4; ++q) o[q] = (_Float16)t[lc + q][n];
    *(half4*)(out + (size_t)(n0 + n) * K + k0 + lc) = o;
  }
}

// ---------------- gate MLP via f16 MFMA -> coef [B, 8] fp32 ----------------
__global__ __launch_bounds__(256) void gate_mfma(
    const float* __restrict__ z, const float* __restrict__ c,
    const _Float16* __restrict__ gw1T,   // [128][576]
    const _Float16* __restrict__ gw2T,   // [128][128]
    const float* __restrict__ gb1, const float* __restrict__ gb2,
    const float* __restrict__ gw3, const float* __restrict__ gb3,
    float* __restrict__ coef)
{
  __shared__ _Float16 h_lds[64][136];
  __shared__ float    h2_lds[64][129];
  __shared__ float    gw3s[128 * 8];
  const int tid = threadIdx.x;
  const int wave = tid >> 6, lane = tid & 63;
  const int quad = lane >> 4, l16 = lane & 15;
  const int r0 = blockIdx.x * 64;

  for (int i = tid; i < 128 * 8; i += 256) gw3s[i] = gw3[i];

  f32x4 acc[8];
  #pragma unroll
  for (int nt = 0; nt < 8; ++nt)
    #pragma unroll
    for (int r = 0; r < 4; ++r) acc[nt][r] = 0.f;

  #pragma unroll 2
  for (int s = 0; s < 18; ++s) {
    const int k0 = s * 32;
    half8 af;
    {
      const size_t row = r0 + wave * 16 + l16;
      const float* src = (k0 < LAT) ? z + row * LAT + k0 + quad * 8
                                    : c + row * FRAME + (k0 - LAT) + quad * 8;
      f32x4 lo = *(const f32x4*)src, hi = *(const f32x4*)(src + 4);
      #pragma unroll
      for (int j = 0; j < 4; ++j) { af[j] = (_Float16)lo[j]; af[j + 4] = (_Float16)hi[j]; }
    }
    half8 bfr[8];
    #pragma unroll
    for (int nt = 0; nt < 8; ++nt)
      bfr[nt] = *(const half8*)(gw1T + (size_t)(nt * 16 + l16) * 576 + k0 + quad * 8);
    #pragma unroll
    for (int nt = 0; nt < 8; ++nt)
      acc[nt] = __builtin_amdgcn_mfma_f32_16x16x32_f16(af, bfr[nt], acc[nt], 0, 0, 0);
  }
  #pragma unroll
  for (int nt = 0; nt < 8; ++nt)
    #pragma unroll
    for (int r = 0; r < 4; ++r) {
      const int rowl = wave * 16 + quad * 4 + r;
      const int col = nt * 16 + l16;
      h_lds[rowl][col] = (_Float16)elu(acc[nt][r] + gb1[col]);
    }
  __syncthreads();

  f32x4 acc2[8];
  #pragma unroll
  for (int nt = 0; nt < 8; ++nt)
    #pragma unroll
    for (int r = 0; r < 4; ++r) acc2[nt][r] = 0.f;
  #pragma unroll
  for (int s = 0; s < 4; ++s) {
    const int k0 = s * 32;
    half8 af = *(const half8*)&h_lds[wave * 16 + l16][k0 + quad * 8];
    half8 bfr[8];
    #pragma unroll
    for (int nt = 0; nt < 8; ++nt)
      bfr[nt] = *(const half8*)(gw2T + (size_t)(nt * 16 + l16) * 128 + k0 + quad * 8);
    #pragma unroll
    for (int nt = 0; nt < 8; ++nt)
      acc2[nt] = __builtin_amdgcn_mfma_f32_16x16x32_f16(af, bfr[nt], acc2[nt], 0, 0, 0);
  }
  #pragma unroll
  for (int nt = 0; nt < 8; ++nt)
    #pragma unroll
    for (int r = 0; r < 4; ++r) {
      const int rowl = wave * 16 + quad * 4 + r;
      const int col = nt * 16 + l16;
      h2_lds[rowl][col] = elu(acc2[nt][r] + gb2[col]);
    }
  __syncthreads();

  {
    const int row = tid >> 2, q = tid & 3;
    float l2v[2] = { gb3[2 * q], gb3[2 * q + 1] };
    for (int k = 0; k < 128; ++k) {
      const float hv = h2_lds[row][k];
      l2v[0] += hv * gw3s[k * 8 + 2 * q];
      l2v[1] += hv * gw3s[k * 8 + 2 * q + 1];
    }
    float m = fmaxf(l2v[0], l2v[1]);
    m = fmaxf(m, __shfl_xor(m, 1));
    m = fmaxf(m, __shfl_xor(m, 2));
    float e0 = expf(l2v[0] - m), e1 = expf(l2v[1] - m);
    float s = e0 + e1;
    s += __shfl_xor(s, 1);
    s += __shfl_xor(s, 2);
    const float inv = 1.f / s;
    float2 o = { e0 * inv, e1 * inv };
    *(float2*)&coef[(size_t)(r0 + row) * NE + 2 * q] = o;
  }
}

// -------- MoE GEMM (r8-verified): tile 128x128, EG experts/block, B-dbuf --------
// A staged once per k0 (reused across EG experts); coef folded into A-fragments.
// part[z] = sum_{e in group} coef_e*(X@W_e + bias_e)   (deterministic partials)
template<int KDIM, int NOUT, int EG>
__global__ __launch_bounds__(256, 2) void gemm_moe(
    const _Float16* __restrict__ X,     // [B][KDIM]
    const _Float16* __restrict__ Wt,    // [NE][NOUT][KDIM]
    const float* __restrict__ coef,     // [B][8]
    const float* __restrict__ bias,     // [8][NOUT]
    float* __restrict__ part)           // [NE/EG][B][NOUT]
{
  __shared__ __align__(16) _Float16 As[128 * 64];
  __shared__ __align__(16) _Float16 Bs[2][128 * 64];
  __shared__ float coefS[128 * EG];
  __shared__ float biasS[EG * 128];

  const int tid = threadIdx.x;
  const int wave = tid >> 6, lane = tid & 63;
  const int wm = wave & 1, wn = wave >> 1;
  const int quad = lane >> 4, l16 = lane & 15;
  const int bm0 = blockIdx.x * 128, bn0 = blockIdx.y * 128;
  const int ebase = blockIdx.z * EG;

  for (int i = tid; i < 128 * EG; i += 256)
    coefS[i] = coef[(size_t)(bm0 + i / EG) * NE + ebase + (i % EG)];
  for (int i = tid; i < EG * 128; i += 256)
    biasS[i] = bias[(size_t)(ebase + (i >> 7)) * NOUT + bn0 + (i & 127)];
  __syncthreads();

  _Float16 ch[4][EG];
  #pragma unroll
  for (int mi = 0; mi < 4; ++mi)
    #pragma unroll
    for (int e = 0; e < EG; ++e)
      ch[mi][e] = (_Float16)coefS[(wm * 64 + mi * 16 + l16) * EG + e];

  f32x4 acc[4][4];
  #pragma unroll
  for (int mi = 0; mi < 4; ++mi)
    #pragma unroll
    for (int ni = 0; ni < 4; ++ni)
      #pragma unroll
      for (int r = 0; r < 4; ++r) acc[mi][ni][r] = 0.f;

  const int srow  = wave * 8 + (lane >> 3);                  // + it*32
  const int skoff = (((lane & 7) ^ ((lane >> 3) & 7)) * 8);  // swizzled src granule

  constexpr int K0S = KDIM / 64;
  for (int k0i = 0; k0i < K0S; ++k0i) {
    const int k0 = k0i * 64;
    // stage A (once per k0) and first expert's B
    #pragma unroll
    for (int it = 0; it < 4; ++it)
      async16(X + (size_t)(bm0 + it * 32 + srow) * KDIM + k0 + skoff,
              &As[it * 2048 + wave * 512]);
    {
      const size_t eoff = (size_t)ebase * NOUT * KDIM;
      #pragma unroll
      for (int it = 0; it < 4; ++it)
        async16(Wt + eoff + (size_t)(bn0 + it * 32 + srow) * KDIM + k0 + skoff,
                &Bs[0][it * 2048 + wave * 512]);
    }
    __syncthreads();

    // A fragments for this k0, reused across the expert group
    half8 af[2][4];
    #pragma unroll
    for (int ks = 0; ks < 2; ++ks)
      #pragma unroll
      for (int mi = 0; mi < 4; ++mi) {
        const int r = wm * 64 + mi * 16 + l16;
        const int g = (ks * 4 + quad) ^ (r & 7);
        af[ks][mi] = *(const half8*)&As[r * 64 + g * 8];
      }

    #pragma unroll
    for (int eo = 0; eo < EG; ++eo) {
      if (eo + 1 < EG) {   // prefetch next expert's B into other buffer
        const size_t eoff = (size_t)(ebase + eo + 1) * NOUT * KDIM;
        #pragma unroll
        for (int it = 0; it < 4; ++it)
          async16(Wt + eoff + (size_t)(bn0 + it * 32 + srow) * KDIM + k0 + skoff,
                  &Bs[(eo + 1) & 1][it * 2048 + wave * 512]);
      }
      const _Float16* bsrc = Bs[eo & 1];
      #pragma unroll
      for (int ks = 0; ks < 2; ++ks) {
        half8 bv[4];
        #pragma unroll
        for (int ni = 0; ni < 4; ++ni) {
          const int r = wn * 64 + ni * 16 + l16;
          const int g = (ks * 4 + quad) ^ (r & 7);
          bv[ni] = *(const half8*)&bsrc[r * 64 + g * 8];
        }
        #pragma unroll
        for (int mi = 0; mi < 4; ++mi) {
          const half8 afs = af[ks][mi] * ch[mi][eo];
          #pragma unroll
          for (int ni = 0; ni < 4; ++ni)
            acc[mi][ni] = __builtin_amdgcn_mfma_f32_16x16x32_f16(
                afs, bv[ni], acc[mi][ni], 0, 0, 0);
        }
      }
      __syncthreads();   // protects Bs reuse and As for next k0's staging
    }
  }

  float* po = part + (size_t)blockIdx.z * B_ * NOUT;
  #pragma unroll
  for (int mi = 0; mi < 4; ++mi)
    #pragma unroll
    for (int r = 0; r < 4; ++r) {
      const int m_loc = wm * 64 + mi * 16 + quad * 4 + r;
      #pragma unroll
      for (int ni = 0; ni < 4; ++ni) {
        const int n_loc = wn * 64 + ni * 16 + l16;
        float v = acc[mi][ni][r];
        #pragma unroll
        for (int e = 0; e < EG; ++e)
          v += coefS[m_loc * EG + e] * biasS[e * 128 + n_loc];
        po[(size_t)(bm0 + m_loc) * NOUT + bn0 + n_loc] = v;
      }
    }
}

// ---- expand: x_next = f16( j<64 ? z : elu(part0+part1) ), vectorized x4 ----
__global__ __launch_bounds__(256) void expand_x(
    const float* __restrict__ part,   // [2][B_][HID]
    const float* __restrict__ z,
    _Float16* __restrict__ xn)        // [B_][IN2]
{
  const int idx4 = blockIdx.x * 256 + threadIdx.x;   // B_*IN2/4 exact
  const int b = idx4 / (IN2 / 4), j = (idx4 - b * (IN2 / 4)) * 4;
  half4 o;
  if (j < LAT) {
    f32x4 v = *(const f32x4*)(z + (size_t)b * LAT + j);
    #pragma unroll
    for (int q = 0; q < 4; ++q) o[q] = (_Float16)v[q];
  } else {
    const int h = j - LAT;
    f32x4 v0 = *(const f32x4*)(part + (size_t)b * HID + h);
    f32x4 v1 = *(const f32x4*)(part + (size_t)B_ * HID + (size_t)b * HID + h);
    #pragma unroll
    for (int q = 0; q < 4; ++q) o[q] = (_Float16)elu(v0[q] + v1[q]);
  }
  *(half4*)(xn + (size_t)b * IN2 + j) = o;
}

// ---- final: out = sum_s part[s], vectorized x4 ----
__global__ __launch_bounds__(256) void final_out(
    const float* __restrict__ part,   // [4][B_][FRAME]
    float* __restrict__ out)
{
  const int idx4 = (blockIdx.x * 256 + threadIdx.x) * 4;   // B_*FRAME exact
  f32x4 v = *(const f32x4*)(part + idx4);
  #pragma unroll
  for (int s = 1; s < 4; ++s) {
    f32x4 p = *(const f32x4*)(part + (size_t)s * B_ * FRAME + idx4);
    #pragma unroll
    for (int q = 0; q < 4; ++q) v[q] += p[q];
  }
  *(f32x4*)(out + idx4) = v;
}

// ============================ launch ============================

extern "C" void kernel_launch(void* const* d_in, const int* in_sizes, int n_in,
                              void* d_out, int out_size, void* d_ws, size_t ws_size,
                              hipStream_t stream)
{
  const float* z   = (const float*)d_in[0];
  const float* c   = (const float*)d_in[1];
  const float* w0  = (const float*)d_in[2];
  const float* b0  = (const float*)d_in[3];
  const float* w1  = (const float*)d_in[4];
  const float* b1  = (const float*)d_in[5];
  const float* w2  = (const float*)d_in[6];
  const float* b2  = (const float*)d_in[7];
  const float* gw1 = (const float*)d_in[8];
  const float* gb1 = (const float*)d_in[9];
  const float* gw2 = (const float*)d_in[10];
  const float* gb2 = (const float*)d_in[11];
  const float* gw3 = (const float*)d_in[12];
  const float* gb3 = (const float*)d_in[13];
  float* out = (float*)d_out;
  char* ws = (char*)d_ws;

  // workspace layout, total 92,585,984 bytes (< proven 122,814,464)
  float*    coef = (float*)    (ws + 0);           //   131,072
  _Float16* x1   = (_Float16*) (ws + 131072);      // 4,718,592
  _Float16* x2   = (_Float16*) (ws + 4849664);     // 8,912,896
  _Float16* x3   = (_Float16*) (ws + 13762560);    // 8,912,896
  _Float16* Wt0  = (_Float16*) (ws + 22675456);    // 9,437,184
  _Float16* Wt1  = (_Float16*) (ws + 32112640);    // 17,825,792
  _Float16* Wt2  = (_Float16*) (ws + 49938432);    // 8,912,896
  float*    part = (float*)    (ws + 58851328);    // 33,554,432
  _Float16* gw1T = (_Float16*) (ws + 92405760);    //   147,456
  _Float16* gw2T = (_Float16*) (ws + 92553216);    //    32,768

  // 4438 transpose blocks + 2304 build_x blocks
  prep_weights<<<4438 + 2304, 256, 0, stream>>>(w0, w1, w2, gw1, gw2, z, c,
                                                Wt0, Wt1, Wt2, gw1T, gw2T,
                                                x1, x2, x3);
  gate_mfma<<<64, 256, 0, stream>>>(z, c, gw1T, gw2T, gb1, gb2, gw3, gb3, coef);

  // layer 1: K=576, N=1024, expert-split 2 x EG4
  gemm_moe<IN1, HID, 4><<<dim3(32, 8, 2), 256, 0, stream>>>(x1, Wt0, coef, b0, part);
  expand_x<<<(B_ * IN2 / 4) / 256, 256, 0, stream>>>(part, z, x2);

  // layer 2: K=1088, N=1024, expert-split 2 x EG4
  gemm_moe<IN2, HID, 4><<<dim3(32, 8, 2), 256, 0, stream>>>(x2, Wt1, coef, b1, part);
  expand_x<<<(B_ * IN2 / 4) / 256, 256, 0, stream>>>(part, z, x3);

  // layer 3: K=1088, N=512, expert-split 4 x EG2 -> partials + final
  gemm_moe<IN2, FRAME, 2><<<dim3(32, 4, 4), 256, 0, stream>>>(x3, Wt2, coef, b2, part);
  final_out<<<(B_ * FRAME / 4) / 256, 256, 0, stream>>>(part, out);
}